// Round 7
// baseline (1499.725 us; speedup 1.0000x reference)
//
#include <hip/hip_runtime.h>
#include <hip/hip_bf16.h>

// Hierarchical BiGRU. Round 7:
//  - gemm_mfma: single-pass bf16 (A hi only; ~0.2% rel added, inside budget),
//    double-buffered A staging (1 barrier/kc), register prefetch of next A.
//  - gru_mfma: M=32 rows/block (2 fragment groups sharing the streamed
//    W_hh B-regs) -> halves the dominant per-step L2 streaming per row.
//    In-register gate combine, gx coalesced dwordx2, h hi/lo dbuf LDS,
//    1 barrier/step.
//  - head_kernel: 256 blocks x 1 wave (was 1 block).
// ws ~167 MB.

typedef __hip_bfloat16 bf16;
typedef short s16x8 __attribute__((ext_vector_type(8)));
typedef float f32x4 __attribute__((ext_vector_type(4)));

#define HDIM 200
#define G3   600
#define NS   2560
#define TW   50
#define ND   256
#define DTR  10

#define GT   13          // tiles per gate (208 cols)
#define NT   39          // stored tiles (3 gates x 13)
#define NTP  40          // packed-B tiles for gemm (last = zero pad)
#define KCH  7           // W_hh k-chunks (200 -> 224)
#define HSTR 232         // h LDS row stride (shorts)
#define KC_W 10          // word x-proj k-chunks (300 -> 320)
#define KC_S 13          // sent x-proj k-chunks (400 -> 416)
#define EMB_ELEMS 15000000

__device__ __forceinline__ float sigf(float x) { return 1.f / (1.f + __expf(-x)); }
__device__ __forceinline__ float tanh_fast(float x) {
    float e = __expf(2.f * x);
    return (e - 1.f) / (e + 1.f);
}
__device__ __forceinline__ unsigned short f2bf(float f) {
    unsigned u = __float_as_uint(f);
    unsigned r = (u + 0x7FFFu + ((u >> 16) & 1u)) >> 16;
    return (unsigned short)r;
}
__device__ __forceinline__ float bf2f(unsigned short b) {
    return __uint_as_float(((unsigned)b) << 16);
}
__device__ __forceinline__ unsigned pk_bf(float a, float b) {
    unsigned ua = __float_as_uint(a) + 0x8000u;
    unsigned ub = __float_as_uint(b) + 0x8000u;
    return __builtin_amdgcn_perm(ub, ua, 0x07060302);
}
// select bf16 #rg (0..3) from a uint2 packed as (rg0,rg1 | rg2,rg3)
__device__ __forceinline__ float bfsel(uint2 v, int rg) {
    unsigned u = (rg & 2) ? v.y : v.x;
    return bf2f((unsigned short)((rg & 1) ? (u >> 16) : (u & 0xFFFFu)));
}

// ---------------- sentence lengths ----------------
__global__ void lens_kernel(const int* __restrict__ x, int* __restrict__ sl) {
    int s = blockIdx.x * 256 + threadIdx.x;
    if (s < NS) {
        int c = 0;
        for (int t = 0; t < TW; ++t) c += (x[s * TW + t] != 0) ? 1 : 0;
        sl[s] = c;
    }
}

// ------------- pre-pack W_hh into per-gate-padded MFMA B-fragments --------
__global__ void prepack_whh(const float* __restrict__ w0, const float* __restrict__ w1,
                            const float* __restrict__ w2, const float* __restrict__ w3,
                            bf16* __restrict__ Bp) {
    int gid = blockIdx.x * 256 + threadIdx.x;
    if (gid >= 4 * NT * KCH * 64) return;
    int lane = gid & 63;
    int f = gid >> 6;
    int kc = f % KCH;
    int tIdx = (f / KCH) % NT;
    int d = f / (KCH * NT);
    const float* w = (d == 0) ? w0 : (d == 1) ? w1 : (d == 2) ? w2 : w3;
    int g = tIdx / GT, j = tIdx % GT;
    int il = j * 16 + (lane & 15);
    int n = g * HDIM + il;
    int kb = kc * 32 + (lane >> 4) * 8;
    unsigned short vals[8] __attribute__((aligned(16)));
#pragma unroll
    for (int jj = 0; jj < 8; ++jj) {
        int k = kb + jj;
        float v = (il < HDIM && k < HDIM) ? w[n * HDIM + k] : 0.f;
        vals[jj] = f2bf(v);
    }
    *reinterpret_cast<float4*>(reinterpret_cast<char*>(Bp) + (size_t)gid * 16) =
        *reinterpret_cast<const float4*>(vals);
}

// ------------- pre-pack W_ih into per-gate-padded B-fragments (single bf16)
__global__ void prepack_bih(const float* __restrict__ w, bf16* __restrict__ Bp,
                            int Kin, int KC) {
    int gid = blockIdx.x * 256 + threadIdx.x;
    if (gid >= NTP * KC * 64) return;
    int lane = gid & 63;
    int f = gid >> 6;
    int kc = f % KC;
    int tIdx = f / KC;
    int g = tIdx / GT, j = tIdx % GT;
    int il = j * 16 + (lane & 15);
    int n = g * HDIM + il;
    int kb = kc * 32 + (lane >> 4) * 8;
    unsigned short vals[8] __attribute__((aligned(16)));
#pragma unroll
    for (int jj = 0; jj < 8; ++jj) {
        int k = kb + jj;
        float v = (tIdx < NT && il < HDIM && k < Kin) ? w[n * Kin + k] : 0.f;
        vals[jj] = f2bf(v);
    }
    *reinterpret_cast<float4*>(reinterpret_cast<char*>(Bp) + (size_t)gid * 16) =
        *reinterpret_cast<const float4*>(vals);
}

// ---------------- MFMA GEMM (single-pass bf16): gx_frag = A @ B ------------
// Rows transposed: row' = t*S + s. GATHER: tok = idx[(row'%S)*Tseq + row'/S].
// Output bf16 fragment layout: byte = ((gmt*39 + gnt)*64 + lane)*8 + reg*2.
template<bool GATHER>
__global__ __launch_bounds__(256) void gemm_mfma(
    const float* __restrict__ Aemb, const float* __restrict__ Afl, int astride,
    const int* __restrict__ idx, int S, int Tseq,
    const bf16* __restrict__ Bp, int KC, bf16* __restrict__ gxOut)
{
    __shared__ __align__(16) unsigned short As[2][128 * 32];  // 16 KB dbuf
    __shared__ int toks[128];

    const int tid = threadIdx.x;
    const int wv = tid >> 6, lane = tid & 63;
    const int bm = blockIdx.x, bn = blockIdx.y;

    if (GATHER && tid < 128) {
        int rp = bm * 128 + tid;
        toks[tid] = idx[(rp % S) * Tseq + (rp / S)];
    }

    int aaddr[4];
#pragma unroll
    for (int mt = 0; mt < 4; ++mt) {
        int row = (wv & 1) * 64 + mt * 16 + (lane & 15);
        aaddr[mt] = row * 32 + (((lane >> 4) ^ ((row >> 1) & 3)) << 3);
    }

    const int srow = tid >> 1, kh = tid & 1;
    const int ssw = (srow >> 1) & 3;

    f32x4 acc[4][4];
#pragma unroll
    for (int i = 0; i < 4; ++i)
#pragma unroll
        for (int j = 0; j < 4; ++j) acc[i][j] = (f32x4){0.f, 0.f, 0.f, 0.f};

    const uint4* bq = reinterpret_cast<const uint4*>(Bp);
    int gnt[4];
#pragma unroll
    for (int j = 0; j < 4; ++j) gnt[j] = bn * 8 + (wv >> 1) * 4 + j;

    __syncthreads();  // toks visible
    const int obase = GATHER ? (toks[srow] * 300 + kh * 16) : 0;
    const float* arow = GATHER ? nullptr
        : Afl + (size_t)(bm * 128 + srow) * astride + kh * 16;

    float4 f[4], fn[4];
#pragma unroll
    for (int j = 0; j < 4; ++j) {
        if (GATHER) {
            int o = obase + j * 4;
            o = (o > EMB_ELEMS - 4) ? (EMB_ELEMS - 4) : o;
            f[j] = *reinterpret_cast<const float4*>(Aemb + o);
        } else {
            f[j] = *reinterpret_cast<const float4*>(arow + j * 4);
        }
    }

    for (int kc = 0; kc < KC; ++kc) {
        unsigned short* Ab = &As[kc & 1][0];
#pragma unroll
        for (int g = 0; g < 2; ++g) {
            uint4 vh;
            vh.x = pk_bf(f[g * 2].x, f[g * 2].y);
            vh.y = pk_bf(f[g * 2].z, f[g * 2].w);
            vh.z = pk_bf(f[g * 2 + 1].x, f[g * 2 + 1].y);
            vh.w = pk_bf(f[g * 2 + 1].z, f[g * 2 + 1].w);
            int slot = (kh * 2 + g) ^ ssw;
            *reinterpret_cast<uint4*>(&Ab[srow * 32 + slot * 8]) = vh;
        }
        __syncthreads();

        // prefetch next A chunk (overlaps MFMA below)
        if (kc + 1 < KC) {
#pragma unroll
            for (int j = 0; j < 4; ++j) {
                if (GATHER) {
                    int o = obase + (kc + 1) * 32 + j * 4;
                    o = (o > EMB_ELEMS - 4) ? (EMB_ELEMS - 4) : o;
                    fn[j] = *reinterpret_cast<const float4*>(Aemb + o);
                } else {
                    fn[j] = *reinterpret_cast<const float4*>(arow + (kc + 1) * 32 + j * 4);
                }
            }
        }

        uint4 b[4];
#pragma unroll
        for (int j = 0; j < 4; ++j)
            b[j] = bq[(size_t)(gnt[j] * KC + kc) * 64 + lane];

        s16x8 ah[4];
#pragma unroll
        for (int mt = 0; mt < 4; ++mt)
            ah[mt] = *reinterpret_cast<const s16x8*>(&Ab[aaddr[mt]]);
#pragma unroll
        for (int mt = 0; mt < 4; ++mt)
#pragma unroll
            for (int j = 0; j < 4; ++j)
                acc[mt][j] = __builtin_amdgcn_mfma_f32_16x16x32_bf16(
                    ah[mt], *reinterpret_cast<const s16x8*>(&b[j]), acc[mt][j], 0, 0, 0);
        if (kc + 1 < KC) {
#pragma unroll
            for (int j = 0; j < 4; ++j) f[j] = fn[j];
        }
    }

#pragma unroll
    for (int mt = 0; mt < 4; ++mt) {
        int gmt = bm * 8 + (wv & 1) * 4 + mt;
#pragma unroll
        for (int j = 0; j < 4; ++j) {
            if (gnt[j] < NT) {
                uint2 v;
                v.x = pk_bf(acc[mt][j][0], acc[mt][j][1]);
                v.y = pk_bf(acc[mt][j][2], acc[mt][j][3]);
                *reinterpret_cast<uint2*>(reinterpret_cast<char*>(gxOut) +
                    ((size_t)(gmt * NT + gnt[j]) * 64 + lane) * 8) = v;
            }
        }
    }
}

// ---------------- MFMA GRU: M=32 rows/block, 1 barrier/step ----------------
// 832 threads = 13 waves; wave w owns within-gate tile j=w for all 3 gates,
// for BOTH 16-row fragment groups (B-regs shared). gx read as coalesced
// dwordx2 fragment layout; h hi/lo double-buffered in LDS.
__global__ __launch_bounds__(832) void gru_mfma(
    const bf16* __restrict__ gx, const bf16* __restrict__ Bp, int dirBase,
    const float* __restrict__ bh, const float* __restrict__ bi,
    const int* __restrict__ lens, float* __restrict__ pool,
    int S, int T, int dirOff, int rev, int poolMode)
{
    __shared__ __align__(16) unsigned short hhi[2][32 * HSTR];  // 29.7 KB
    __shared__ __align__(16) unsigned short hlo[2][32 * HSTR];  // 29.7 KB

    const int tid = threadIdx.x;
    const int w = tid >> 6, lane = tid & 63;
    const int quad = lane >> 4, c = lane & 15;
    const int row0 = blockIdx.x * 32;
    const int i = w * 16 + c;
    const bool iv = (i < HDIM);

    for (int p = tid; p < 32 * HSTR; p += 832) {
        hhi[0][p] = 0; hhi[1][p] = 0; hlo[0][p] = 0; hlo[1][p] = 0;
    }

    float bhr = 0.f, bhz = 0.f, bhn = 0.f, binv = 0.f;
    if (iv) {
        bhr = bh[i] + bi[i];
        bhz = bh[HDIM + i] + bi[HDIM + i];
        bhn = bh[2 * HDIM + i];
        binv = bi[2 * HDIM + i];
    }
    int slen[2][4];
    float hreg[2][4], pacc[2][4];
#pragma unroll
    for (int mg = 0; mg < 2; ++mg)
#pragma unroll
        for (int rg = 0; rg < 4; ++rg) {
            int L = lens[row0 + mg * 16 + quad * 4 + rg];
            if (L < 0) L = 0;
            if (L > T) L = T;
            slen[mg][rg] = L;
            hreg[mg][rg] = 0.f; pacc[mg][rg] = 0.f;
        }

    const uint4* bq = reinterpret_cast<const uint4*>(Bp);
    size_t bo[3];
#pragma unroll
    for (int g = 0; g < 3; ++g)
        bo[g] = (size_t)(dirBase + g * GT + w) * KCH * 64 + lane;

    const char* gxb = reinterpret_cast<const char*>(gx);
    int am[2], hw[2];
#pragma unroll
    for (int mg = 0; mg < 2; ++mg) {
        am[mg] = (mg * 16 + c) * HSTR + quad * 8;
        hw[mg] = (mg * 16 + quad * 4) * HSTR + i;
    }
    const int SG = S >> 4;  // 16-row groups

    __syncthreads();

    for (int ts = 0; ts < T; ++ts) {
        const int t = rev ? (T - 1 - ts) : ts;
        const int cur = ts & 1, nxt = cur ^ 1;
        const long long g0 = (long long)t * SG + blockIdx.x * 2;

        uint2 gxv[2][3];
#pragma unroll
        for (int mg = 0; mg < 2; ++mg)
#pragma unroll
            for (int g = 0; g < 3; ++g)
                gxv[mg][g] = *reinterpret_cast<const uint2*>(
                    gxb + (((g0 + mg) * NT + g * GT + w) * 64 + lane) * 8);

        f32x4 a[2][3];
#pragma unroll
        for (int mg = 0; mg < 2; ++mg)
#pragma unroll
            for (int g = 0; g < 3; ++g) a[mg][g] = (f32x4){0.f, 0.f, 0.f, 0.f};

#pragma unroll
        for (int kc = 0; kc < KCH; ++kc) {
            uint4 b0 = bq[bo[0] + kc * 64];
            uint4 b1 = bq[bo[1] + kc * 64];
            uint4 b2 = bq[bo[2] + kc * 64];
#pragma unroll
            for (int mg = 0; mg < 2; ++mg) {
                s16x8 ah = *reinterpret_cast<const s16x8*>(&hhi[cur][am[mg] + kc * 32]);
                s16x8 al = *reinterpret_cast<const s16x8*>(&hlo[cur][am[mg] + kc * 32]);
                a[mg][0] = __builtin_amdgcn_mfma_f32_16x16x32_bf16(ah, *reinterpret_cast<const s16x8*>(&b0), a[mg][0], 0, 0, 0);
                a[mg][1] = __builtin_amdgcn_mfma_f32_16x16x32_bf16(ah, *reinterpret_cast<const s16x8*>(&b1), a[mg][1], 0, 0, 0);
                a[mg][2] = __builtin_amdgcn_mfma_f32_16x16x32_bf16(ah, *reinterpret_cast<const s16x8*>(&b2), a[mg][2], 0, 0, 0);
                a[mg][0] = __builtin_amdgcn_mfma_f32_16x16x32_bf16(al, *reinterpret_cast<const s16x8*>(&b0), a[mg][0], 0, 0, 0);
                a[mg][1] = __builtin_amdgcn_mfma_f32_16x16x32_bf16(al, *reinterpret_cast<const s16x8*>(&b1), a[mg][1], 0, 0, 0);
                a[mg][2] = __builtin_amdgcn_mfma_f32_16x16x32_bf16(al, *reinterpret_cast<const s16x8*>(&b2), a[mg][2], 0, 0, 0);
            }
        }

        if (iv) {
#pragma unroll
            for (int mg = 0; mg < 2; ++mg)
#pragma unroll
                for (int rg = 0; rg < 4; ++rg) {
                    float xr = bfsel(gxv[mg][0], rg);
                    float xz = bfsel(gxv[mg][1], rg);
                    float xn = bfsel(gxv[mg][2], rg);
                    float r = sigf(xr + a[mg][0][rg] + bhr);
                    float z = sigf(xz + a[mg][1][rg] + bhz);
                    float n = tanh_fast((xn + binv) + r * (a[mg][2][rg] + bhn));
                    float hnew = (1.f - z) * n + z * hreg[mg][rg];
                    hreg[mg][rg] = hnew;
                    unsigned short hi = f2bf(hnew);
                    hhi[nxt][hw[mg] + rg * HSTR] = hi;
                    hlo[nxt][hw[mg] + rg * HSTR] = f2bf(hnew - bf2f(hi));
                    if (t < slen[mg][rg]) pacc[mg][rg] += hnew;
                }
        }
        __syncthreads();
    }

    if (iv) {
#pragma unroll
        for (int mg = 0; mg < 2; ++mg)
#pragma unroll
            for (int rg = 0; rg < 4; ++rg) {
                int sg = row0 + mg * 16 + quad * 4 + rg;
                int L = slen[mg][rg];
                float v = (L > 0) ? pacc[mg][rg] / (float)L : 0.f;
                int prow = poolMode ? ((sg % 10) * ND + sg / 10) : sg;
                pool[(size_t)prow * 400 + dirOff + i] = v;
            }
    }
}

// ---------------- heads: 256 blocks x 1 wave ----------------
__global__ __launch_bounds__(64) void head_kernel(
    const float* __restrict__ d_pool, const int* __restrict__ doc_lens,
    const float* __restrict__ doc_w, const float* __restrict__ doc_b,
    const float* __restrict__ sent_w, const float* __restrict__ sent_b,
    float* __restrict__ out)
{
    const int d = blockIdx.x;
    const int lane = threadIdx.x;

    // soff = sum_{j<d} clamp(doc_lens[j]); wave-parallel
    int part = 0;
#pragma unroll
    for (int rep = 0; rep < 4; ++rep) {
        int j = lane + rep * 64;
        int v = doc_lens[j];
        v = (v < 0) ? 0 : (v > DTR ? DTR : v);
        if (j < d) part += v;
    }
#pragma unroll
    for (int off = 32; off; off >>= 1) part += __shfl_down(part, off);
    int soff = __shfl(part, 0);

    int dl = doc_lens[d];
    dl = (dl < 0) ? 0 : (dl > DTR ? DTR : dl);
    const float* dv = d_pool + (size_t)d * 400;

    for (int o = 0; o <= dl; ++o) {
        const float* wrow = (o == 0) ? doc_w : sent_w + (o - 1) * 400;
        float s = 0.f;
        for (int f = lane; f < 400; f += 64) s += dv[f] * wrow[f];
#pragma unroll
        for (int off = 32; off; off >>= 1) s += __shfl_down(s, off);
        if (lane == 0) {
            float bias = (o == 0) ? doc_b[0] : sent_b[o - 1];
            out[(o == 0) ? d : (ND + soff + (o - 1))] = sigf(s + bias);
        }
    }
}

// --------------------------------------------------------------------------
extern "C" void kernel_launch(void* const* d_in, const int* in_sizes, int n_in,
                              void* d_out, int out_size, void* d_ws, size_t ws_size,
                              hipStream_t stream) {
    const int*   x        = (const int*)d_in[0];
    const int*   doc_lens = (const int*)d_in[2];
    const float* emb      = (const float*)d_in[3];
    const float* wf_ih = (const float*)d_in[4];
    const float* wf_hh = (const float*)d_in[5];
    const float* wf_bi = (const float*)d_in[6];
    const float* wf_bh = (const float*)d_in[7];
    const float* wb_ih = (const float*)d_in[8];
    const float* wb_hh = (const float*)d_in[9];
    const float* wb_bi = (const float*)d_in[10];
    const float* wb_bh = (const float*)d_in[11];
    const float* sf_ih = (const float*)d_in[12];
    const float* sf_hh = (const float*)d_in[13];
    const float* sf_bi = (const float*)d_in[14];
    const float* sf_bh = (const float*)d_in[15];
    const float* sb_ih = (const float*)d_in[16];
    const float* sb_hh = (const float*)d_in[17];
    const float* sb_bi = (const float*)d_in[18];
    const float* sb_bh = (const float*)d_in[19];
    const float* doc_w  = (const float*)d_in[20];
    const float* doc_b  = (const float*)d_in[21];
    const float* sent_w = (const float*)d_in[22];
    const float* sent_b = (const float*)d_in[23];

    char* ws = (char*)d_ws;
    const size_t OFF_GX  = 0;                        // 8000*39*512 = 159,744,000
    const size_t OFF_SIN = 159744000;                // 2560*400*4 + 64pad
    const size_t OFF_D   = OFF_SIN + 4096256;        // 256*400*4
    const size_t OFF_SL  = OFF_D + 409600;           // 2560*4
    const size_t OFF_BHH = OFF_SL + 10240;           // 4*39*7*1024 = 1,118,208
    const size_t OFF_BIW = OFF_BHH + 1118208;        // 2*40*10*1024 = 819,200
    const size_t OFF_BIS = OFF_BIW + 819200;         // 2*40*13*1024 = 1,064,960
    bf16*  gx     = (bf16*)(ws + OFF_GX);
    float* s_in   = (float*)(ws + OFF_SIN);
    float* dpool  = (float*)(ws + OFF_D);
    int*   sl     = (int*)(ws + OFF_SL);
    bf16*  Bhh    = (bf16*)(ws + OFF_BHH);
    bf16*  BiW0   = (bf16*)(ws + OFF_BIW);
    bf16*  BiW1   = BiW0 + NTP * KC_W * 64 * 8;
    bf16*  BiS0   = (bf16*)(ws + OFF_BIS);
    bf16*  BiS1   = BiS0 + NTP * KC_S * 64 * 8;

    prepack_whh<<<(4 * NT * KCH * 64 + 255) / 256, 256, 0, stream>>>(
        wf_hh, wb_hh, sf_hh, sb_hh, Bhh);
    prepack_bih<<<(NTP * KC_W * 64 + 255) / 256, 256, 0, stream>>>(wf_ih, BiW0, 300, KC_W);
    prepack_bih<<<(NTP * KC_W * 64 + 255) / 256, 256, 0, stream>>>(wb_ih, BiW1, 300, KC_W);
    prepack_bih<<<(NTP * KC_S * 64 + 255) / 256, 256, 0, stream>>>(sf_ih, BiS0, 400, KC_S);
    prepack_bih<<<(NTP * KC_S * 64 + 255) / 256, 256, 0, stream>>>(sb_ih, BiS1, 400, KC_S);
    lens_kernel<<<(NS + 255) / 256, 256, 0, stream>>>(x, sl);

    // word level, forward
    gemm_mfma<true><<<dim3(1000, 5), 256, 0, stream>>>(emb, nullptr, 0, x, NS, TW, BiW0, KC_W, gx);
    gru_mfma<<<NS / 32, 832, 0, stream>>>(gx, Bhh, 0 * NT, wf_bh, wf_bi, sl, s_in, NS, TW, 0, 0, 1);
    // word level, backward
    gemm_mfma<true><<<dim3(1000, 5), 256, 0, stream>>>(emb, nullptr, 0, x, NS, TW, BiW1, KC_W, gx);
    gru_mfma<<<NS / 32, 832, 0, stream>>>(gx, Bhh, 1 * NT, wb_bh, wb_bi, sl, s_in, NS, TW, HDIM, 1, 1);
    // sentence level, forward (A = s_in, rows already transposed t*ND+d)
    gemm_mfma<false><<<dim3(20, 5), 256, 0, stream>>>(nullptr, s_in, 400, nullptr, ND, DTR, BiS0, KC_S, gx);
    gru_mfma<<<ND / 32, 832, 0, stream>>>(gx, Bhh, 2 * NT, sf_bh, sf_bi, doc_lens, dpool, ND, DTR, 0, 0, 0);
    // sentence level, backward
    gemm_mfma<false><<<dim3(20, 5), 256, 0, stream>>>(nullptr, s_in, 400, nullptr, ND, DTR, BiS1, KC_S, gx);
    gru_mfma<<<ND / 32, 832, 0, stream>>>(gx, Bhh, 3 * NT, sb_bh, sb_bi, doc_lens, dpool, ND, DTR, HDIM, 1, 0);

    head_kernel<<<ND, 64, 0, stream>>>(dpool, doc_lens, doc_w, doc_b, sent_w, sent_b, (float*)d_out);
}

// Round 8
// 911.695 us; speedup vs baseline: 1.6450x; 1.6450x over previous
//
#include <hip/hip_runtime.h>
#include <hip/hip_bf16.h>

// Hierarchical BiGRU. Round 8:
//  - gru_mfma: M=16, 512 thr / 8 waves, W_hh fully VGPR-RESIDENT
//    (waves 0-4 own within-gate tiles {w, 8+w}, waves 5-7 own {w}; max
//    2x3x7 = 42 frags = 168 VGPRs). Zero per-step L2 B-streaming (was the
//    r6/r7 bottleneck: 280 KB/block/step ~ 5.1K cyc/step at 56 B/cy/CU).
//    In-register combine, gx coalesced dwordx2, h hi/lo dbuf LDS, 1
//    barrier/step. 160 blocks (full CU spread).
//  - gemm_mfma: 8 waves, wave owns 4 m-tiles x 10 n-tiles (full N=624 per
//    block, grid (M/128,1)) -> A gathered ONCE (was 5x re-gather, FETCH
//    426 MB). A dbuf LDS, reg prefetch, B streamed from hot L2.
// ws ~167 MB.

typedef __hip_bfloat16 bf16;
typedef short s16x8 __attribute__((ext_vector_type(8)));
typedef float f32x4 __attribute__((ext_vector_type(4)));

#define HDIM 200
#define NS   2560
#define TW   50
#define ND   256
#define DTR  10

#define GT   13          // tiles per gate (208 cols)
#define NT   39          // stored tiles (3 gates x 13)
#define NTP  40          // packed-B tiles for gemm (last = zero pad)
#define KCH  7           // W_hh k-chunks (200 -> 224)
#define HSTR 232         // h LDS row stride (shorts)
#define KC_W 10          // word x-proj k-chunks (300 -> 320)
#define KC_S 13          // sent x-proj k-chunks (400 -> 416)
#define EMB_ELEMS 15000000

__device__ __forceinline__ float sigf(float x) { return 1.f / (1.f + __expf(-x)); }
__device__ __forceinline__ float tanh_fast(float x) {
    float e = __expf(2.f * x);
    return (e - 1.f) / (e + 1.f);
}
__device__ __forceinline__ unsigned short f2bf(float f) {
    unsigned u = __float_as_uint(f);
    unsigned r = (u + 0x7FFFu + ((u >> 16) & 1u)) >> 16;
    return (unsigned short)r;
}
__device__ __forceinline__ float bf2f(unsigned short b) {
    return __uint_as_float(((unsigned)b) << 16);
}
__device__ __forceinline__ unsigned pk_bf(float a, float b) {
    unsigned ua = __float_as_uint(a) + 0x8000u;
    unsigned ub = __float_as_uint(b) + 0x8000u;
    return __builtin_amdgcn_perm(ub, ua, 0x07060302);
}
// select bf16 #rg (0..3) from a uint2 packed as (rg0,rg1 | rg2,rg3)
__device__ __forceinline__ float bfsel(uint2 v, int rg) {
    unsigned u = (rg & 2) ? v.y : v.x;
    return bf2f((unsigned short)((rg & 1) ? (u >> 16) : (u & 0xFFFFu)));
}

// ---------------- sentence lengths ----------------
__global__ void lens_kernel(const int* __restrict__ x, int* __restrict__ sl) {
    int s = blockIdx.x * 256 + threadIdx.x;
    if (s < NS) {
        int c = 0;
        for (int t = 0; t < TW; ++t) c += (x[s * TW + t] != 0) ? 1 : 0;
        sl[s] = c;
    }
}

// ------------- pre-pack W_hh into per-gate-padded MFMA B-fragments --------
__global__ void prepack_whh(const float* __restrict__ w0, const float* __restrict__ w1,
                            const float* __restrict__ w2, const float* __restrict__ w3,
                            bf16* __restrict__ Bp) {
    int gid = blockIdx.x * 256 + threadIdx.x;
    if (gid >= 4 * NT * KCH * 64) return;
    int lane = gid & 63;
    int f = gid >> 6;
    int kc = f % KCH;
    int tIdx = (f / KCH) % NT;
    int d = f / (KCH * NT);
    const float* w = (d == 0) ? w0 : (d == 1) ? w1 : (d == 2) ? w2 : w3;
    int g = tIdx / GT, j = tIdx % GT;
    int il = j * 16 + (lane & 15);
    int n = g * HDIM + il;
    int kb = kc * 32 + (lane >> 4) * 8;
    unsigned short vals[8] __attribute__((aligned(16)));
#pragma unroll
    for (int jj = 0; jj < 8; ++jj) {
        int k = kb + jj;
        float v = (il < HDIM && k < HDIM) ? w[n * HDIM + k] : 0.f;
        vals[jj] = f2bf(v);
    }
    *reinterpret_cast<float4*>(reinterpret_cast<char*>(Bp) + (size_t)gid * 16) =
        *reinterpret_cast<const float4*>(vals);
}

// ------------- pre-pack W_ih into per-gate-padded B-fragments (single bf16)
__global__ void prepack_bih(const float* __restrict__ w, bf16* __restrict__ Bp,
                            int Kin, int KC) {
    int gid = blockIdx.x * 256 + threadIdx.x;
    if (gid >= NTP * KC * 64) return;
    int lane = gid & 63;
    int f = gid >> 6;
    int kc = f % KC;
    int tIdx = f / KC;
    int g = tIdx / GT, j = tIdx % GT;
    int il = j * 16 + (lane & 15);
    int n = g * HDIM + il;
    int kb = kc * 32 + (lane >> 4) * 8;
    unsigned short vals[8] __attribute__((aligned(16)));
#pragma unroll
    for (int jj = 0; jj < 8; ++jj) {
        int k = kb + jj;
        float v = (tIdx < NT && il < HDIM && k < Kin) ? w[n * Kin + k] : 0.f;
        vals[jj] = f2bf(v);
    }
    *reinterpret_cast<float4*>(reinterpret_cast<char*>(Bp) + (size_t)gid * 16) =
        *reinterpret_cast<const float4*>(vals);
}

// ---------------- MFMA GEMM: full N per block, A gathered once -------------
// 512 thr / 8 waves: wave = (m_w = wv&1) x (n_w = wv>>1); wave covers
// 4 m-tiles x 10 n-tiles. Rows transposed: row' = t*S + s.
// GATHER: tok = idx[(row'%S)*Tseq + row'/S].
// Output bf16 fragment layout: byte = ((gmt*39 + gnt)*64 + lane)*8 + reg*2.
template<bool GATHER>
__global__ __launch_bounds__(512, 2) void gemm_mfma(
    const float* __restrict__ Aemb, const float* __restrict__ Afl, int astride,
    const int* __restrict__ idx, int S, int Tseq,
    const bf16* __restrict__ Bp, int KC, bf16* __restrict__ gxOut)
{
    __shared__ __align__(16) unsigned short As[2][128 * 32];  // 16 KB dbuf
    __shared__ int toks[128];

    const int tid = threadIdx.x;
    const int wv = tid >> 6, lane = tid & 63;
    const int bm = blockIdx.x;
    const int m_w = wv & 1, n_w = wv >> 1;

    if (GATHER && tid < 128) {
        int rp = bm * 128 + tid;
        toks[tid] = idx[(rp % S) * Tseq + (rp / S)];
    }

    int aaddr[4];
#pragma unroll
    for (int mt = 0; mt < 4; ++mt) {
        int row = m_w * 64 + mt * 16 + (lane & 15);
        aaddr[mt] = row * 32 + (((lane >> 4) ^ ((row >> 1) & 3)) << 3);
    }

    // staging: thread -> (row srow, quarter qk); 8 f32 per thread per kc
    const int srow = tid >> 2, qk = tid & 3;
    const int ssw = (srow >> 1) & 3;

    f32x4 acc[4][10];
#pragma unroll
    for (int i = 0; i < 4; ++i)
#pragma unroll
        for (int j = 0; j < 10; ++j) acc[i][j] = (f32x4){0.f, 0.f, 0.f, 0.f};

    const uint4* bq = reinterpret_cast<const uint4*>(Bp);

    __syncthreads();  // toks visible
    const int obase = GATHER ? (toks[srow] * 300 + qk * 8) : 0;
    const float* arow = GATHER ? nullptr
        : Afl + (size_t)(bm * 128 + srow) * astride + qk * 8;

    float4 f[2], fn[2];
#pragma unroll
    for (int j = 0; j < 2; ++j) {
        if (GATHER) {
            int o = obase + j * 4;
            o = (o > EMB_ELEMS - 4) ? (EMB_ELEMS - 4) : o;
            f[j] = *reinterpret_cast<const float4*>(Aemb + o);
        } else {
            f[j] = *reinterpret_cast<const float4*>(arow + j * 4);
        }
    }

    for (int kc = 0; kc < KC; ++kc) {
        unsigned short* Ab = &As[kc & 1][0];
        {
            uint4 vh;
            vh.x = pk_bf(f[0].x, f[0].y);
            vh.y = pk_bf(f[0].z, f[0].w);
            vh.z = pk_bf(f[1].x, f[1].y);
            vh.w = pk_bf(f[1].z, f[1].w);
            int slot = qk ^ ssw;
            *reinterpret_cast<uint4*>(&Ab[srow * 32 + slot * 8]) = vh;
        }
        __syncthreads();

        // prefetch next A chunk (overlaps MFMA below)
        if (kc + 1 < KC) {
#pragma unroll
            for (int j = 0; j < 2; ++j) {
                if (GATHER) {
                    int o = obase + (kc + 1) * 32 + j * 4;
                    o = (o > EMB_ELEMS - 4) ? (EMB_ELEMS - 4) : o;
                    fn[j] = *reinterpret_cast<const float4*>(Aemb + o);
                } else {
                    fn[j] = *reinterpret_cast<const float4*>(arow + (kc + 1) * 32 + j * 4);
                }
            }
        }

        s16x8 ah[4];
#pragma unroll
        for (int mt = 0; mt < 4; ++mt)
            ah[mt] = *reinterpret_cast<const s16x8*>(&Ab[aaddr[mt]]);

        // two half-passes of 5 n-tiles to cap live B registers
#pragma unroll
        for (int half = 0; half < 2; ++half) {
            uint4 b[5];
#pragma unroll
            for (int j = 0; j < 5; ++j) {
                int gnt = n_w * 10 + half * 5 + j;
                b[j] = bq[(size_t)(gnt * KC + kc) * 64 + lane];
            }
#pragma unroll
            for (int mt = 0; mt < 4; ++mt)
#pragma unroll
                for (int j = 0; j < 5; ++j)
                    acc[mt][half * 5 + j] = __builtin_amdgcn_mfma_f32_16x16x32_bf16(
                        ah[mt], *reinterpret_cast<const s16x8*>(&b[j]),
                        acc[mt][half * 5 + j], 0, 0, 0);
        }
        if (kc + 1 < KC) { f[0] = fn[0]; f[1] = fn[1]; }
    }

#pragma unroll
    for (int mt = 0; mt < 4; ++mt) {
        int gmt = bm * 8 + m_w * 4 + mt;
#pragma unroll
        for (int j = 0; j < 10; ++j) {
            int gnt = n_w * 10 + j;
            if (gnt < NT) {
                uint2 v;
                v.x = pk_bf(acc[mt][j][0], acc[mt][j][1]);
                v.y = pk_bf(acc[mt][j][2], acc[mt][j][3]);
                *reinterpret_cast<uint2*>(reinterpret_cast<char*>(gxOut) +
                    ((size_t)(gmt * NT + gnt) * 64 + lane) * 8) = v;
            }
        }
    }
}

// ---------------- MFMA GRU: VGPR-resident W_hh, 1 barrier/step -------------
// 512 thr / 8 waves, M=16 rows/block. Wave w owns within-gate tiles
// jl = {w, 8+w (w<5)} for ALL 3 gates, B-frags resident in registers.
// In-register gate combine; gx coalesced dwordx2; h hi/lo dbuf in LDS.
__global__ __launch_bounds__(512, 2) void gru_mfma(
    const bf16* __restrict__ gx, const bf16* __restrict__ Bp, int dirBase,
    const float* __restrict__ bh, const float* __restrict__ bi,
    const int* __restrict__ lens, float* __restrict__ pool,
    int S, int T, int dirOff, int rev, int poolMode)
{
    __shared__ __align__(16) unsigned short hhi[2][16 * HSTR];  // 14.8 KB
    __shared__ __align__(16) unsigned short hlo[2][16 * HSTR];  // 14.8 KB

    const int tid = threadIdx.x;
    const int w = tid >> 6, lane = tid & 63;
    const int quad = lane >> 4, c = lane & 15;
    const int row0 = blockIdx.x * 16;
    const int nj = (w < 5) ? 2 : 1;
    const int jl[2] = {w, 8 + w};

    for (int p = tid; p < 16 * HSTR; p += 512) {
        hhi[0][p] = 0; hhi[1][p] = 0; hlo[0][p] = 0; hlo[1][p] = 0;
    }

    int ii[2]; bool iv[2];
    float bhr[2], bhz[2], bhn[2], binv[2];
#pragma unroll
    for (int jj = 0; jj < 2; ++jj) {
        int i = jl[jj] * 16 + c;
        ii[jj] = i;
        iv[jj] = (jj < nj) && (i < HDIM);
        bhr[jj] = bhz[jj] = bhn[jj] = binv[jj] = 0.f;
        if (iv[jj]) {
            bhr[jj] = bh[i] + bi[i];
            bhz[jj] = bh[HDIM + i] + bi[HDIM + i];
            bhn[jj] = bh[2 * HDIM + i];
            binv[jj] = bi[2 * HDIM + i];
        }
    }
    int slen[4];
    float hreg[2][4], pacc[2][4];
#pragma unroll
    for (int rg = 0; rg < 4; ++rg) {
        int L = lens[row0 + quad * 4 + rg];
        if (L < 0) L = 0;
        if (L > T) L = T;
        slen[rg] = L;
#pragma unroll
        for (int jj = 0; jj < 2; ++jj) { hreg[jj][rg] = 0.f; pacc[jj][rg] = 0.f; }
    }

    // resident B fragments
    const float4* Bq = reinterpret_cast<const float4*>(Bp);
    s16x8 bfr[2][3][7];
#pragma unroll
    for (int jj = 0; jj < 2; ++jj) {
        if (jj < nj) {
#pragma unroll
            for (int g = 0; g < 3; ++g)
#pragma unroll
                for (int kc = 0; kc < KCH; ++kc) {
                    int fidx = (dirBase + g * GT + jl[jj]) * KCH + kc;
                    float4 raw = Bq[(size_t)fidx * 64 + lane];
                    bfr[jj][g][kc] = *reinterpret_cast<s16x8*>(&raw);
                }
        }
    }

    const char* gxb = reinterpret_cast<const char*>(gx);
    const int am = c * HSTR + quad * 8;
    const int SG = S >> 4;
    __syncthreads();

    for (int ts = 0; ts < T; ++ts) {
        const int t = rev ? (T - 1 - ts) : ts;
        const int cur = ts & 1, nxt = cur ^ 1;
        const long long gg = (long long)t * SG + blockIdx.x;

        uint2 gxv[2][3];
#pragma unroll
        for (int jj = 0; jj < 2; ++jj)
            if (jj < nj)
#pragma unroll
                for (int g = 0; g < 3; ++g)
                    gxv[jj][g] = *reinterpret_cast<const uint2*>(
                        gxb + ((gg * NT + g * GT + jl[jj]) * 64 + lane) * 8);

        f32x4 acc[2][3];
#pragma unroll
        for (int jj = 0; jj < 2; ++jj)
#pragma unroll
            for (int g = 0; g < 3; ++g) acc[jj][g] = (f32x4){0.f, 0.f, 0.f, 0.f};

#pragma unroll
        for (int kc = 0; kc < KCH; ++kc) {
            s16x8 ah = *reinterpret_cast<const s16x8*>(&hhi[cur][am + kc * 32]);
            s16x8 al = *reinterpret_cast<const s16x8*>(&hlo[cur][am + kc * 32]);
#pragma unroll
            for (int jj = 0; jj < 2; ++jj) {
                if (jj < nj) {
#pragma unroll
                    for (int g = 0; g < 3; ++g) {
                        acc[jj][g] = __builtin_amdgcn_mfma_f32_16x16x32_bf16(
                            ah, bfr[jj][g][kc], acc[jj][g], 0, 0, 0);
                        acc[jj][g] = __builtin_amdgcn_mfma_f32_16x16x32_bf16(
                            al, bfr[jj][g][kc], acc[jj][g], 0, 0, 0);
                    }
                }
            }
        }

#pragma unroll
        for (int jj = 0; jj < 2; ++jj) {
            if (iv[jj]) {
#pragma unroll
                for (int rg = 0; rg < 4; ++rg) {
                    float xr = bfsel(gxv[jj][0], rg);
                    float xz = bfsel(gxv[jj][1], rg);
                    float xn = bfsel(gxv[jj][2], rg);
                    float r = sigf(xr + acc[jj][0][rg] + bhr[jj]);
                    float z = sigf(xz + acc[jj][1][rg] + bhz[jj]);
                    float n = tanh_fast((xn + binv[jj]) + r * (acc[jj][2][rg] + bhn[jj]));
                    float hnew = (1.f - z) * n + z * hreg[jj][rg];
                    hreg[jj][rg] = hnew;
                    unsigned short hi = f2bf(hnew);
                    hhi[nxt][(quad * 4 + rg) * HSTR + ii[jj]] = hi;
                    hlo[nxt][(quad * 4 + rg) * HSTR + ii[jj]] = f2bf(hnew - bf2f(hi));
                    if (t < slen[rg]) pacc[jj][rg] += hnew;
                }
            }
        }
        __syncthreads();
    }

#pragma unroll
    for (int jj = 0; jj < 2; ++jj) {
        if (iv[jj]) {
#pragma unroll
            for (int rg = 0; rg < 4; ++rg) {
                int sg = row0 + quad * 4 + rg;
                int L = slen[rg];
                float v = (L > 0) ? pacc[jj][rg] / (float)L : 0.f;
                int prow = poolMode ? ((sg % 10) * ND + sg / 10) : sg;
                pool[(size_t)prow * 400 + dirOff + ii[jj]] = v;
            }
        }
    }
}

// ---------------- heads: 256 blocks x 1 wave ----------------
__global__ __launch_bounds__(64) void head_kernel(
    const float* __restrict__ d_pool, const int* __restrict__ doc_lens,
    const float* __restrict__ doc_w, const float* __restrict__ doc_b,
    const float* __restrict__ sent_w, const float* __restrict__ sent_b,
    float* __restrict__ out)
{
    const int d = blockIdx.x;
    const int lane = threadIdx.x;

    int part = 0;
#pragma unroll
    for (int rep = 0; rep < 4; ++rep) {
        int j = lane + rep * 64;
        int v = doc_lens[j];
        v = (v < 0) ? 0 : (v > DTR ? DTR : v);
        if (j < d) part += v;
    }
#pragma unroll
    for (int off = 32; off; off >>= 1) part += __shfl_down(part, off);
    int soff = __shfl(part, 0);

    int dl = doc_lens[d];
    dl = (dl < 0) ? 0 : (dl > DTR ? DTR : dl);
    const float* dv = d_pool + (size_t)d * 400;

    for (int o = 0; o <= dl; ++o) {
        const float* wrow = (o == 0) ? doc_w : sent_w + (o - 1) * 400;
        float s = 0.f;
        for (int f = lane; f < 400; f += 64) s += dv[f] * wrow[f];
#pragma unroll
        for (int off = 32; off; off >>= 1) s += __shfl_down(s, off);
        if (lane == 0) {
            float bias = (o == 0) ? doc_b[0] : sent_b[o - 1];
            out[(o == 0) ? d : (ND + soff + (o - 1))] = sigf(s + bias);
        }
    }
}

// --------------------------------------------------------------------------
extern "C" void kernel_launch(void* const* d_in, const int* in_sizes, int n_in,
                              void* d_out, int out_size, void* d_ws, size_t ws_size,
                              hipStream_t stream) {
    const int*   x        = (const int*)d_in[0];
    const int*   doc_lens = (const int*)d_in[2];
    const float* emb      = (const float*)d_in[3];
    const float* wf_ih = (const float*)d_in[4];
    const float* wf_hh = (const float*)d_in[5];
    const float* wf_bi = (const float*)d_in[6];
    const float* wf_bh = (const float*)d_in[7];
    const float* wb_ih = (const float*)d_in[8];
    const float* wb_hh = (const float*)d_in[9];
    const float* wb_bi = (const float*)d_in[10];
    const float* wb_bh = (const float*)d_in[11];
    const float* sf_ih = (const float*)d_in[12];
    const float* sf_hh = (const float*)d_in[13];
    const float* sf_bi = (const float*)d_in[14];
    const float* sf_bh = (const float*)d_in[15];
    const float* sb_ih = (const float*)d_in[16];
    const float* sb_hh = (const float*)d_in[17];
    const float* sb_bi = (const float*)d_in[18];
    const float* sb_bh = (const float*)d_in[19];
    const float* doc_w  = (const float*)d_in[20];
    const float* doc_b  = (const float*)d_in[21];
    const float* sent_w = (const float*)d_in[22];
    const float* sent_b = (const float*)d_in[23];

    char* ws = (char*)d_ws;
    const size_t OFF_GX  = 0;                        // 8000*39*512 = 159,744,000
    const size_t OFF_SIN = 159744000;                // 2560*400*4 + 64B pad
    const size_t OFF_D   = OFF_SIN + 4096256;        // 256*400*4
    const size_t OFF_SL  = OFF_D + 409600;           // 2560*4
    const size_t OFF_BHH = OFF_SL + 10240;           // 4*39*7*1024 = 1,118,208
    const size_t OFF_BIW = OFF_BHH + 1118208;        // 2*40*10*1024 = 819,200
    const size_t OFF_BIS = OFF_BIW + 819200;         // 2*40*13*1024 = 1,064,960
    bf16*  gx     = (bf16*)(ws + OFF_GX);
    float* s_in   = (float*)(ws + OFF_SIN);
    float* dpool  = (float*)(ws + OFF_D);
    int*   sl     = (int*)(ws + OFF_SL);
    bf16*  Bhh    = (bf16*)(ws + OFF_BHH);
    bf16*  BiW0   = (bf16*)(ws + OFF_BIW);
    bf16*  BiW1   = BiW0 + NTP * KC_W * 64 * 8;
    bf16*  BiS0   = (bf16*)(ws + OFF_BIS);
    bf16*  BiS1   = BiS0 + NTP * KC_S * 64 * 8;

    prepack_whh<<<(4 * NT * KCH * 64 + 255) / 256, 256, 0, stream>>>(
        wf_hh, wb_hh, sf_hh, sb_hh, Bhh);
    prepack_bih<<<(NTP * KC_W * 64 + 255) / 256, 256, 0, stream>>>(wf_ih, BiW0, 300, KC_W);
    prepack_bih<<<(NTP * KC_W * 64 + 255) / 256, 256, 0, stream>>>(wb_ih, BiW1, 300, KC_W);
    prepack_bih<<<(NTP * KC_S * 64 + 255) / 256, 256, 0, stream>>>(sf_ih, BiS0, 400, KC_S);
    prepack_bih<<<(NTP * KC_S * 64 + 255) / 256, 256, 0, stream>>>(sb_ih, BiS1, 400, KC_S);
    lens_kernel<<<(NS + 255) / 256, 256, 0, stream>>>(x, sl);

    // word level, forward
    gemm_mfma<true><<<1000, 512, 0, stream>>>(emb, nullptr, 0, x, NS, TW, BiW0, KC_W, gx);
    gru_mfma<<<NS / 16, 512, 0, stream>>>(gx, Bhh, 0 * NT, wf_bh, wf_bi, sl, s_in, NS, TW, 0, 0, 1);
    // word level, backward
    gemm_mfma<true><<<1000, 512, 0, stream>>>(emb, nullptr, 0, x, NS, TW, BiW1, KC_W, gx);
    gru_mfma<<<NS / 16, 512, 0, stream>>>(gx, Bhh, 1 * NT, wb_bh, wb_bi, sl, s_in, NS, TW, HDIM, 1, 1);
    // sentence level, forward (A = s_in, rows already transposed t*ND+d)
    gemm_mfma<false><<<20, 512, 0, stream>>>(nullptr, s_in, 400, nullptr, ND, DTR, BiS0, KC_S, gx);
    gru_mfma<<<ND / 16, 512, 0, stream>>>(gx, Bhh, 2 * NT, sf_bh, sf_bi, doc_lens, dpool, ND, DTR, 0, 0, 0);
    // sentence level, backward
    gemm_mfma<false><<<20, 512, 0, stream>>>(nullptr, s_in, 400, nullptr, ND, DTR, BiS1, KC_S, gx);
    gru_mfma<<<ND / 16, 512, 0, stream>>>(gx, Bhh, 3 * NT, sb_bh, sb_bi, doc_lens, dpool, ND, DTR, HDIM, 1, 0);

    head_kernel<<<ND, 64, 0, stream>>>(dpool, doc_lens, doc_w, doc_b, sent_w, sent_b, (float*)d_out);
}

// Round 10
// 774.590 us; speedup vs baseline: 1.9362x; 1.1770x over previous
//
#include <hip/hip_runtime.h>
#include <hip/hip_bf16.h>

// Hierarchical BiGRU. Round 10 = round 9 with the cvt_pkrtz type fixed
// (__builtin_amdgcn_cvt_pkrtz returns __fp16 ext_vector(2), not _Float16x2).
// Full f16 pipeline:
//  - f16 mantissa (10b) => single-pass h recurrence (NO hi/lo compensation):
//    GRU MFMA count halves. All MFMA ops f32_16x16x32_f16.
//  - gru_mfma: 832 thr / 13 waves, wave w owns within-gate tile w for all 3
//    gates; resident B = 21 frags = 84 VGPRs (fits 128-VGPR/4-wave budget,
//    unlike r8's 168 which the compiler silently spilled to L2 re-streams).
//    1 barrier/step, in-register combine, gx coalesced dwordx2.
//  - biases folded into gx via per-column table in GEMM epilogue
//    (r/z: bi+bh, n: bi; bh_n stays in GRU).
// ws ~167 MB.

typedef __hip_bfloat16 bf16;
typedef _Float16 h16x8 __attribute__((ext_vector_type(8)));
typedef __fp16 fp16x2 __attribute__((ext_vector_type(2)));
typedef float f32x4 __attribute__((ext_vector_type(4)));

#define HDIM 200
#define NS   2560
#define TW   50
#define ND   256
#define DTR  10

#define GT   13          // tiles per gate (208 cols)
#define NT   39          // stored tiles (3 gates x 13)
#define NTP  40          // packed-B tiles for gemm (last = zero pad)
#define KCH  7           // W_hh k-chunks (200 -> 224)
#define HSTR 232         // h LDS row stride (halfs)
#define KC_W 10          // word x-proj k-chunks (300 -> 320)
#define KC_S 13          // sent x-proj k-chunks (400 -> 416)
#define EMB_ELEMS 15000000

__device__ __forceinline__ float sigf(float x) { return 1.f / (1.f + __expf(-x)); }
__device__ __forceinline__ float tanh_fast(float x) {
    float e = __expf(2.f * x);
    return (e - 1.f) / (e + 1.f);
}
__device__ __forceinline__ unsigned short f2h(float x) {
    union { _Float16 h; unsigned short u; } v;
    v.h = (_Float16)x;
    return v.u;
}
__device__ __forceinline__ float h2f(unsigned short u) {
    union { _Float16 h; unsigned short u; } v;
    v.u = u;
    return (float)v.h;
}
// pack 2 f32 -> 2 f16 (RTZ, 1 instr), a low, b high
__device__ __forceinline__ unsigned pk2h(float a, float b) {
    union { fp16x2 p; unsigned u; } v;
    v.p = __builtin_amdgcn_cvt_pkrtz(a, b);
    return v.u;
}
// select f16 #rg (0..3) from a uint2 packed as (rg0,rg1 | rg2,rg3)
__device__ __forceinline__ float hfsel(uint2 v, int rg) {
    unsigned u = (rg & 2) ? v.y : v.x;
    return h2f((unsigned short)((rg & 1) ? (u >> 16) : (u & 0xFFFFu)));
}

// ---------------- sentence lengths ----------------
__global__ void lens_kernel(const int* __restrict__ x, int* __restrict__ sl) {
    int s = blockIdx.x * 256 + threadIdx.x;
    if (s < NS) {
        int c = 0;
        for (int t = 0; t < TW; ++t) c += (x[s * TW + t] != 0) ? 1 : 0;
        sl[s] = c;
    }
}

// ------------- pre-pack W_hh into per-gate-padded MFMA B-fragments (f16) --
__global__ void prepack_whh(const float* __restrict__ w0, const float* __restrict__ w1,
                            const float* __restrict__ w2, const float* __restrict__ w3,
                            unsigned short* __restrict__ Bp) {
    int gid = blockIdx.x * 256 + threadIdx.x;
    if (gid >= 4 * NT * KCH * 64) return;
    int lane = gid & 63;
    int f = gid >> 6;
    int kc = f % KCH;
    int tIdx = (f / KCH) % NT;
    int d = f / (KCH * NT);
    const float* w = (d == 0) ? w0 : (d == 1) ? w1 : (d == 2) ? w2 : w3;
    int g = tIdx / GT, j = tIdx % GT;
    int il = j * 16 + (lane & 15);
    int n = g * HDIM + il;
    int kb = kc * 32 + (lane >> 4) * 8;
    unsigned short vals[8] __attribute__((aligned(16)));
#pragma unroll
    for (int jj = 0; jj < 8; ++jj) {
        int k = kb + jj;
        float v = (il < HDIM && k < HDIM) ? w[n * HDIM + k] : 0.f;
        vals[jj] = f2h(v);
    }
    *reinterpret_cast<float4*>(reinterpret_cast<char*>(Bp) + (size_t)gid * 16) =
        *reinterpret_cast<const float4*>(vals);
}

// ------------- pre-pack W_ih into per-gate-padded B-fragments (f16) -------
__global__ void prepack_bih(const float* __restrict__ w, unsigned short* __restrict__ Bp,
                            int Kin, int KC) {
    int gid = blockIdx.x * 256 + threadIdx.x;
    if (gid >= NTP * KC * 64) return;
    int lane = gid & 63;
    int f = gid >> 6;
    int kc = f % KC;
    int tIdx = f / KC;
    int g = tIdx / GT, j = tIdx % GT;
    int il = j * 16 + (lane & 15);
    int n = g * HDIM + il;
    int kb = kc * 32 + (lane >> 4) * 8;
    unsigned short vals[8] __attribute__((aligned(16)));
#pragma unroll
    for (int jj = 0; jj < 8; ++jj) {
        int k = kb + jj;
        float v = (tIdx < NT && il < HDIM && k < Kin) ? w[n * Kin + k] : 0.f;
        vals[jj] = f2h(v);
    }
    *reinterpret_cast<float4*>(reinterpret_cast<char*>(Bp) + (size_t)gid * 16) =
        *reinterpret_cast<const float4*>(vals);
}

// ------------- per-column folded bias tables: bt[dir][624] ----------------
// col = g*208 + i: g<2 -> bi[g*200+i]+bh[g*200+i]; g==2 -> bi[400+i] (bh_n
// stays in the GRU, inside the r* term).
__global__ void prepack_bias(
    const float* bi0, const float* bh0, const float* bi1, const float* bh1,
    const float* bi2, const float* bh2, const float* bi3, const float* bh3,
    float* __restrict__ bt) {
    int gid = blockIdx.x * 256 + threadIdx.x;
    if (gid >= 4 * 624) return;
    int d = gid / 624, col = gid % 624;
    int g = col / 208, i = col % 208;
    const float* bi = (d == 0) ? bi0 : (d == 1) ? bi1 : (d == 2) ? bi2 : bi3;
    const float* bh = (d == 0) ? bh0 : (d == 1) ? bh1 : (d == 2) ? bh2 : bh3;
    float v = 0.f;
    if (i < HDIM) v = (g < 2) ? (bi[g * HDIM + i] + bh[g * HDIM + i]) : bi[2 * HDIM + i];
    bt[gid] = v;
}

// ---------------- MFMA GEMM (f16): gx_frag = A @ B + bt -------------------
// 512 thr / 8 waves: wave = (m_w = wv&1) x (n_w = wv>>1); wave covers
// 4 m-tiles x 10 n-tiles. Rows transposed: row' = t*S + s.
// GATHER: tok = idx[(row'%S)*Tseq + row'/S].
// Output f16 fragment layout: byte = ((gmt*39 + gnt)*64 + lane)*8 + reg*2.
template<bool GATHER>
__global__ __launch_bounds__(512, 2) void gemm_mfma(
    const float* __restrict__ Aemb, const float* __restrict__ Afl, int astride,
    const int* __restrict__ idx, int S, int Tseq,
    const unsigned short* __restrict__ Bp, int KC,
    const float* __restrict__ bt, unsigned short* __restrict__ gxOut)
{
    __shared__ __align__(16) unsigned short As[2][128 * 32];  // 16 KB dbuf
    __shared__ int toks[128];

    const int tid = threadIdx.x;
    const int wv = tid >> 6, lane = tid & 63;
    const int bm = blockIdx.x;
    const int m_w = wv & 1, n_w = wv >> 1;

    if (GATHER && tid < 128) {
        int rp = bm * 128 + tid;
        toks[tid] = idx[(rp % S) * Tseq + (rp / S)];
    }

    int aaddr[4];
#pragma unroll
    for (int mt = 0; mt < 4; ++mt) {
        int row = m_w * 64 + mt * 16 + (lane & 15);
        aaddr[mt] = row * 32 + (((lane >> 4) ^ ((row >> 1) & 3)) << 3);
    }

    // staging: thread -> (row srow, quarter qk); 8 f32 per thread per kc
    const int srow = tid >> 2, qk = tid & 3;
    const int ssw = (srow >> 1) & 3;

    f32x4 acc[4][10];
#pragma unroll
    for (int i = 0; i < 4; ++i)
#pragma unroll
        for (int j = 0; j < 10; ++j) acc[i][j] = (f32x4){0.f, 0.f, 0.f, 0.f};

    const uint4* bq = reinterpret_cast<const uint4*>(Bp);

    __syncthreads();  // toks visible
    const int obase = GATHER ? (toks[srow] * 300 + qk * 8) : 0;
    const float* arow = GATHER ? nullptr
        : Afl + (size_t)(bm * 128 + srow) * astride + qk * 8;

    float4 f[2], fn[2];
#pragma unroll
    for (int j = 0; j < 2; ++j) {
        if (GATHER) {
            int o = obase + j * 4;
            o = (o > EMB_ELEMS - 4) ? (EMB_ELEMS - 4) : o;
            f[j] = *reinterpret_cast<const float4*>(Aemb + o);
        } else {
            f[j] = *reinterpret_cast<const float4*>(arow + j * 4);
        }
    }

    for (int kc = 0; kc < KC; ++kc) {
        unsigned short* Ab = &As[kc & 1][0];
        {
            uint4 vh;
            vh.x = pk2h(f[0].x, f[0].y);
            vh.y = pk2h(f[0].z, f[0].w);
            vh.z = pk2h(f[1].x, f[1].y);
            vh.w = pk2h(f[1].z, f[1].w);
            int slot = qk ^ ssw;
            *reinterpret_cast<uint4*>(&Ab[srow * 32 + slot * 8]) = vh;
        }
        __syncthreads();

        // prefetch next A chunk (overlaps MFMA below)
        if (kc + 1 < KC) {
#pragma unroll
            for (int j = 0; j < 2; ++j) {
                if (GATHER) {
                    int o = obase + (kc + 1) * 32 + j * 4;
                    o = (o > EMB_ELEMS - 4) ? (EMB_ELEMS - 4) : o;
                    fn[j] = *reinterpret_cast<const float4*>(Aemb + o);
                } else {
                    fn[j] = *reinterpret_cast<const float4*>(arow + (kc + 1) * 32 + j * 4);
                }
            }
        }

        h16x8 ah[4];
#pragma unroll
        for (int mt = 0; mt < 4; ++mt)
            ah[mt] = *reinterpret_cast<const h16x8*>(&Ab[aaddr[mt]]);

        // two half-passes of 5 n-tiles to cap live B registers
#pragma unroll
        for (int half = 0; half < 2; ++half) {
            uint4 b[5];
#pragma unroll
            for (int j = 0; j < 5; ++j) {
                int gnt = n_w * 10 + half * 5 + j;
                b[j] = bq[(size_t)(gnt * KC + kc) * 64 + lane];
            }
#pragma unroll
            for (int mt = 0; mt < 4; ++mt)
#pragma unroll
                for (int j = 0; j < 5; ++j)
                    acc[mt][half * 5 + j] = __builtin_amdgcn_mfma_f32_16x16x32_f16(
                        ah[mt], *reinterpret_cast<const h16x8*>(&b[j]),
                        acc[mt][half * 5 + j], 0, 0, 0);
        }
        if (kc + 1 < KC) { f[0] = fn[0]; f[1] = fn[1]; }
    }

    // folded bias per column
    float btv[10];
#pragma unroll
    for (int j = 0; j < 10; ++j) {
        int gnt = n_w * 10 + j;
        btv[j] = (gnt < NT) ? bt[gnt * 16 + (lane & 15)] : 0.f;
    }

#pragma unroll
    for (int mt = 0; mt < 4; ++mt) {
        int gmt = bm * 8 + m_w * 4 + mt;
#pragma unroll
        for (int j = 0; j < 10; ++j) {
            int gnt = n_w * 10 + j;
            if (gnt < NT) {
                uint2 v;
                v.x = pk2h(acc[mt][j][0] + btv[j], acc[mt][j][1] + btv[j]);
                v.y = pk2h(acc[mt][j][2] + btv[j], acc[mt][j][3] + btv[j]);
                *reinterpret_cast<uint2*>(reinterpret_cast<char*>(gxOut) +
                    ((size_t)(gmt * NT + gnt) * 64 + lane) * 8) = v;
            }
        }
    }
}

// ---------------- MFMA GRU: f16, resident W_hh, 1 barrier/step -------------
// 832 thr / 13 waves, M=16 rows/block. Wave w owns within-gate tile w for
// ALL 3 gates: resident B = 21 frags = 84 VGPRs. Single f16 h (no hi/lo),
// double-buffered in LDS. In-register combine; gx coalesced dwordx2.
__global__ __launch_bounds__(832) void gru_mfma(
    const unsigned short* __restrict__ gx, const unsigned short* __restrict__ Bp,
    int dirBase, const float* __restrict__ bh,
    const int* __restrict__ lens, float* __restrict__ pool,
    int S, int T, int dirOff, int rev, int poolMode)
{
    __shared__ __align__(16) unsigned short hh[2][16 * HSTR];  // 14.5 KB

    const int tid = threadIdx.x;
    const int w = tid >> 6, lane = tid & 63;
    const int quad = lane >> 4, c = lane & 15;
    const int row0 = blockIdx.x * 16;
    const int i = w * 16 + c;
    const bool iv = (i < HDIM);

    for (int p = tid; p < 16 * HSTR; p += 832) { hh[0][p] = 0; hh[1][p] = 0; }

    const float bhn = iv ? bh[2 * HDIM + i] : 0.f;

    int slen[4];
    float hreg[4], pacc[4];
#pragma unroll
    for (int rg = 0; rg < 4; ++rg) {
        int L = lens[row0 + quad * 4 + rg];
        if (L < 0) L = 0;
        if (L > T) L = T;
        slen[rg] = L;
        hreg[rg] = 0.f; pacc[rg] = 0.f;
    }

    // resident B fragments: 3 gates x 7 k-chunks
    const float4* Bq = reinterpret_cast<const float4*>(Bp);
    h16x8 bfr[3][7];
#pragma unroll
    for (int g = 0; g < 3; ++g)
#pragma unroll
        for (int kc = 0; kc < KCH; ++kc) {
            int fidx = (dirBase + g * GT + w) * KCH + kc;
            float4 raw = Bq[(size_t)fidx * 64 + lane];
            bfr[g][kc] = *reinterpret_cast<h16x8*>(&raw);
        }

    const char* gxb = reinterpret_cast<const char*>(gx);
    const int am = c * HSTR + quad * 8;
    const int SG = S >> 4;
    const int hw0 = (quad * 4) * HSTR + i;
    __syncthreads();

    for (int ts = 0; ts < T; ++ts) {
        const int t = rev ? (T - 1 - ts) : ts;
        const int cur = ts & 1, nxt = cur ^ 1;
        const long long gg = (long long)t * SG + blockIdx.x;

        uint2 gxv[3];
#pragma unroll
        for (int g = 0; g < 3; ++g)
            gxv[g] = *reinterpret_cast<const uint2*>(
                gxb + ((gg * NT + g * GT + w) * 64 + lane) * 8);

        f32x4 a0 = (f32x4){0.f, 0.f, 0.f, 0.f}, a1 = a0, a2 = a0;
#pragma unroll
        for (int kc = 0; kc < KCH; ++kc) {
            h16x8 ah = *reinterpret_cast<const h16x8*>(&hh[cur][am + kc * 32]);
            a0 = __builtin_amdgcn_mfma_f32_16x16x32_f16(ah, bfr[0][kc], a0, 0, 0, 0);
            a1 = __builtin_amdgcn_mfma_f32_16x16x32_f16(ah, bfr[1][kc], a1, 0, 0, 0);
            a2 = __builtin_amdgcn_mfma_f32_16x16x32_f16(ah, bfr[2][kc], a2, 0, 0, 0);
        }

        if (iv) {
#pragma unroll
            for (int rg = 0; rg < 4; ++rg) {
                float xr = hfsel(gxv[0], rg);   // includes bi_r + bh_r
                float xz = hfsel(gxv[1], rg);   // includes bi_z + bh_z
                float xn = hfsel(gxv[2], rg);   // includes bi_n
                float r = sigf(xr + a0[rg]);
                float z = sigf(xz + a1[rg]);
                float n = tanh_fast(xn + r * (a2[rg] + bhn));
                float hnew = (1.f - z) * n + z * hreg[rg];
                hreg[rg] = hnew;
                hh[nxt][hw0 + rg * HSTR] = f2h(hnew);
                if (t < slen[rg]) pacc[rg] += hnew;
            }
        }
        __syncthreads();
    }

    if (iv) {
#pragma unroll
        for (int rg = 0; rg < 4; ++rg) {
            int sg = row0 + quad * 4 + rg;
            int L = slen[rg];
            float v = (L > 0) ? pacc[rg] / (float)L : 0.f;
            int prow = poolMode ? ((sg % 10) * ND + sg / 10) : sg;
            pool[(size_t)prow * 400 + dirOff + i] = v;
        }
    }
}

// ---------------- heads: 256 blocks x 1 wave ----------------
__global__ __launch_bounds__(64) void head_kernel(
    const float* __restrict__ d_pool, const int* __restrict__ doc_lens,
    const float* __restrict__ doc_w, const float* __restrict__ doc_b,
    const float* __restrict__ sent_w, const float* __restrict__ sent_b,
    float* __restrict__ out)
{
    const int d = blockIdx.x;
    const int lane = threadIdx.x;

    int part = 0;
#pragma unroll
    for (int rep = 0; rep < 4; ++rep) {
        int j = lane + rep * 64;
        int v = doc_lens[j];
        v = (v < 0) ? 0 : (v > DTR ? DTR : v);
        if (j < d) part += v;
    }
#pragma unroll
    for (int off = 32; off; off >>= 1) part += __shfl_down(part, off);
    int soff = __shfl(part, 0);

    int dl = doc_lens[d];
    dl = (dl < 0) ? 0 : (dl > DTR ? DTR : dl);
    const float* dv = d_pool + (size_t)d * 400;

    for (int o = 0; o <= dl; ++o) {
        const float* wrow = (o == 0) ? doc_w : sent_w + (o - 1) * 400;
        float s = 0.f;
        for (int f = lane; f < 400; f += 64) s += dv[f] * wrow[f];
#pragma unroll
        for (int off = 32; off; off >>= 1) s += __shfl_down(s, off);
        if (lane == 0) {
            float bias = (o == 0) ? doc_b[0] : sent_b[o - 1];
            out[(o == 0) ? d : (ND + soff + (o - 1))] = sigf(s + bias);
        }
    }
}

// --------------------------------------------------------------------------
extern "C" void kernel_launch(void* const* d_in, const int* in_sizes, int n_in,
                              void* d_out, int out_size, void* d_ws, size_t ws_size,
                              hipStream_t stream) {
    const int*   x        = (const int*)d_in[0];
    const int*   doc_lens = (const int*)d_in[2];
    const float* emb      = (const float*)d_in[3];
    const float* wf_ih = (const float*)d_in[4];
    const float* wf_hh = (const float*)d_in[5];
    const float* wf_bi = (const float*)d_in[6];
    const float* wf_bh = (const float*)d_in[7];
    const float* wb_ih = (const float*)d_in[8];
    const float* wb_hh = (const float*)d_in[9];
    const float* wb_bi = (const float*)d_in[10];
    const float* wb_bh = (const float*)d_in[11];
    const float* sf_ih = (const float*)d_in[12];
    const float* sf_hh = (const float*)d_in[13];
    const float* sf_bi = (const float*)d_in[14];
    const float* sf_bh = (const float*)d_in[15];
    const float* sb_ih = (const float*)d_in[16];
    const float* sb_hh = (const float*)d_in[17];
    const float* sb_bi = (const float*)d_in[18];
    const float* sb_bh = (const float*)d_in[19];
    const float* doc_w  = (const float*)d_in[20];
    const float* doc_b  = (const float*)d_in[21];
    const float* sent_w = (const float*)d_in[22];
    const float* sent_b = (const float*)d_in[23];

    char* ws = (char*)d_ws;
    const size_t OFF_GX  = 0;                        // 8000*39*512 = 159,744,000
    const size_t OFF_SIN = 159744000;                // 2560*400*4 + 64B pad
    const size_t OFF_D   = OFF_SIN + 4096256;        // 256*400*4
    const size_t OFF_SL  = OFF_D + 409600;           // 2560*4
    const size_t OFF_BHH = OFF_SL + 10240;           // 4*39*7*1024 = 1,118,208
    const size_t OFF_BIW = OFF_BHH + 1118208;        // 2*40*10*1024 = 819,200
    const size_t OFF_BIS = OFF_BIW + 819200;         // 2*40*13*1024 = 1,064,960
    const size_t OFF_BT  = OFF_BIS + 1064960;        // 4*624*4 = 9,984
    unsigned short* gx   = (unsigned short*)(ws + OFF_GX);
    float* s_in   = (float*)(ws + OFF_SIN);
    float* dpool  = (float*)(ws + OFF_D);
    int*   sl     = (int*)(ws + OFF_SL);
    unsigned short* Bhh  = (unsigned short*)(ws + OFF_BHH);
    unsigned short* BiW0 = (unsigned short*)(ws + OFF_BIW);
    unsigned short* BiW1 = BiW0 + NTP * KC_W * 64 * 8;
    unsigned short* BiS0 = (unsigned short*)(ws + OFF_BIS);
    unsigned short* BiS1 = BiS0 + NTP * KC_S * 64 * 8;
    float* bt     = (float*)(ws + OFF_BT);  // 4 x 624

    prepack_whh<<<(4 * NT * KCH * 64 + 255) / 256, 256, 0, stream>>>(
        wf_hh, wb_hh, sf_hh, sb_hh, Bhh);
    prepack_bih<<<(NTP * KC_W * 64 + 255) / 256, 256, 0, stream>>>(wf_ih, BiW0, 300, KC_W);
    prepack_bih<<<(NTP * KC_W * 64 + 255) / 256, 256, 0, stream>>>(wb_ih, BiW1, 300, KC_W);
    prepack_bih<<<(NTP * KC_S * 64 + 255) / 256, 256, 0, stream>>>(sf_ih, BiS0, 400, KC_S);
    prepack_bih<<<(NTP * KC_S * 64 + 255) / 256, 256, 0, stream>>>(sb_ih, BiS1, 400, KC_S);
    prepack_bias<<<(4 * 624 + 255) / 256, 256, 0, stream>>>(
        wf_bi, wf_bh, wb_bi, wb_bh, sf_bi, sf_bh, sb_bi, sb_bh, bt);
    lens_kernel<<<(NS + 255) / 256, 256, 0, stream>>>(x, sl);

    // word level, forward
    gemm_mfma<true><<<1000, 512, 0, stream>>>(emb, nullptr, 0, x, NS, TW, BiW0, KC_W, bt + 0 * 624, gx);
    gru_mfma<<<NS / 16, 832, 0, stream>>>(gx, Bhh, 0 * NT, wf_bh, sl, s_in, NS, TW, 0, 0, 1);
    // word level, backward
    gemm_mfma<true><<<1000, 512, 0, stream>>>(emb, nullptr, 0, x, NS, TW, BiW1, KC_W, bt + 1 * 624, gx);
    gru_mfma<<<NS / 16, 832, 0, stream>>>(gx, Bhh, 1 * NT, wb_bh, sl, s_in, NS, TW, HDIM, 1, 1);
    // sentence level, forward (A = s_in, rows already transposed t*ND+d)
    gemm_mfma<false><<<20, 512, 0, stream>>>(nullptr, s_in, 400, nullptr, ND, DTR, BiS0, KC_S, bt + 2 * 624, gx);
    gru_mfma<<<ND / 16, 832, 0, stream>>>(gx, Bhh, 2 * NT, sf_bh, doc_lens, dpool, ND, DTR, 0, 0, 0);
    // sentence level, backward
    gemm_mfma<false><<<20, 512, 0, stream>>>(nullptr, s_in, 400, nullptr, ND, DTR, BiS1, KC_S, bt + 3 * 624, gx);
    gru_mfma<<<ND / 16, 832, 0, stream>>>(gx, Bhh, 3 * NT, sb_bh, doc_lens, dpool, ND, DTR, HDIM, 1, 0);

    head_kernel<<<ND, 64, 0, stream>>>(dpool, doc_lens, doc_w, doc_b, sent_w, sent_b, (float*)d_out);
}